// Round 1
// baseline (36000.092 us; speedup 1.0000x reference)
//
#include <hip/hip_runtime.h>
#include <hip/hip_bf16.h>
#include <hip/hip_cooperative_groups.h>

namespace cg = cooperative_groups;

typedef __attribute__((ext_vector_type(8))) short short8;
typedef __attribute__((ext_vector_type(4))) float f32x4;
typedef __attribute__((ext_vector_type(4))) unsigned int uint4_t;
typedef __attribute__((ext_vector_type(4))) unsigned short ushort4_t;

#define BB 8
#define SS 2048
#define DD 1024
#define EE 4096

__device__ __forceinline__ unsigned short f2bf(float f) {
  unsigned int u = __builtin_bit_cast(unsigned int, f);
  u += 0x7fffu + ((u >> 16) & 1u);
  return (unsigned short)(u >> 16);
}
__device__ __forceinline__ float bf2f(unsigned short h) {
  unsigned int u = ((unsigned int)h) << 16;
  return __builtin_bit_cast(float, u);
}

// ---------------- Kernel 1: cast W_w and U_w fp32 -> bf16 ----------------
__global__ void cvt2_kernel(const float* __restrict__ Wf, const float* __restrict__ Uf,
                            unsigned short* __restrict__ Wb, unsigned short* __restrict__ Ub) {
  const int n4 = EE * DD / 4;  // 1048576 float4s per matrix
  for (int i = blockIdx.x * blockDim.x + threadIdx.x; i < n4; i += gridDim.x * blockDim.x) {
    float4 w = ((const float4*)Wf)[i];
    float4 u = ((const float4*)Uf)[i];
    ushort4_t wo, uo;
    wo[0] = f2bf(w.x); wo[1] = f2bf(w.y); wo[2] = f2bf(w.z); wo[3] = f2bf(w.w);
    uo[0] = f2bf(u.x); uo[1] = f2bf(u.y); uo[2] = f2bf(u.z); uo[3] = f2bf(u.w);
    ((ushort4_t*)Wb)[i] = wo;
    ((ushort4_t*)Ub)[i] = uo;
  }
}

// ---------------- Kernel 2: LayerNorm -> bf16 h_out ----------------
// one block (256 thr) per row; row = b*S + s; D=1024 -> 4 floats/thread
__global__ void ln_kernel(const float* __restrict__ x, const float* __restrict__ gamma,
                          const float* __restrict__ beta, unsigned short* __restrict__ hout) {
  int row = blockIdx.x;
  int t = threadIdx.x;
  int wid = t >> 6, lane = t & 63;
  float4 v = ((const float4*)(x + (size_t)row * DD))[t];
  float s = v.x + v.y + v.z + v.w;
  float s2 = v.x * v.x + v.y * v.y + v.z * v.z + v.w * v.w;
  for (int o = 32; o; o >>= 1) { s += __shfl_down(s, o); s2 += __shfl_down(s2, o); }
  __shared__ float rs[4], rq[4];
  if (lane == 0) { rs[wid] = s; rq[wid] = s2; }
  __syncthreads();
  float sum = rs[0] + rs[1] + rs[2] + rs[3];
  float sum2 = rq[0] + rq[1] + rq[2] + rq[3];
  float mean = sum * (1.0f / DD);
  float var = sum2 * (1.0f / DD) - mean * mean;
  float rstd = rsqrtf(var + 1e-5f);
  float4 g = ((const float4*)gamma)[t];
  float4 bt = ((const float4*)beta)[t];
  ushort4_t o4;
  o4[0] = f2bf((v.x - mean) * rstd * g.x + bt.x);
  o4[1] = f2bf((v.y - mean) * rstd * g.y + bt.y);
  o4[2] = f2bf((v.z - mean) * rstd * g.z + bt.z);
  o4[3] = f2bf((v.w - mean) * rstd * g.w + bt.w);
  ((ushort4_t*)(hout + (size_t)row * DD))[t] = o4;
}

// ---------------- Kernel 3: GEMM xW[s,b,e] = hout[(b,s),:] . W_w[e,:] + W_b[e] ----------------
// A: (16384 x 1024) bf16 row-major, B: W_w (4096 x 1024) bf16 row-major (K-contig = B^T layout)
// block = 4 waves; each wave does a 16x64 tile (4 accumulators); block tile = 16 rows x 256 cols
__launch_bounds__(256)
__global__ void gemm_xw(const unsigned short* __restrict__ A, const unsigned short* __restrict__ Bm,
                        const float* __restrict__ bias, unsigned short* __restrict__ xw) {
  int rowTile = blockIdx.x;   // 0..1023
  int colGrp = blockIdx.y;    // 0..15
  int wid = threadIdx.x >> 6;
  int lane = threadIdx.x & 63;
  int colBase = colGrp * 256 + wid * 64;
  int r = rowTile * 16 + (lane & 15);  // A-frag row
  int kb = (lane >> 4) * 8;            // k sub-block
  f32x4 acc[4] = {};
  for (int k0 = 0; k0 < DD; k0 += 32) {
    short8 af = *(const short8*)(A + (size_t)r * DD + k0 + kb);
#pragma unroll
    for (int c = 0; c < 4; c++) {
      int col = colBase + c * 16 + (lane & 15);
      short8 bf = *(const short8*)(Bm + (size_t)col * DD + k0 + kb);
      acc[c] = __builtin_amdgcn_mfma_f32_16x16x32_bf16(af, bf, acc[c], 0, 0, 0);
    }
  }
#pragma unroll
  for (int c = 0; c < 4; c++) {
    int col = colBase + c * 16 + (lane & 15);
    float bv = bias[col];
#pragma unroll
    for (int r2 = 0; r2 < 4; r2++) {
      int R = rowTile * 16 + (lane >> 4) * 4 + r2;  // C-frag row = (b,s) row
      int b = R >> 11, sIdx = R & 2047;             // S = 2048
      xw[(size_t)sIdx * (BB * EE) + (size_t)b * EE + col] = f2bf(acc[c][r2] + bv);
    }
  }
}

// ---------------- Kernel 4: cooperative sLSTM scan ----------------
// 64 blocks x 256 thr (4 waves). Block bl owns d in [bl*16, bl*16+16).
// Wave g (0..3) owns gate g: e-cols g*1024 + bl*16 + 0..15, U slice held in 128 VGPRs.
// h (16x1024, rows 8..15 zero pad) double-buffered in global; staged to swizzled LDS each step.
__launch_bounds__(256, 1)
__global__ void scan_kernel(const unsigned short* __restrict__ xw, const unsigned short* __restrict__ Ub,
                            const float* __restrict__ x, float* __restrict__ out,
                            unsigned short* __restrict__ hbuf) {
  cg::grid_group grid = cg::this_grid();
  int bl = blockIdx.x;
  int tid = threadIdx.x;
  int wid = tid >> 6, lane = tid & 63;
  int d0 = bl * 16;

  __shared__ __align__(16) unsigned short h_lds[16 * 1024];  // 32KB, XOR-swizzled
  __shared__ float g_lds[4][8][16];

  // preload U fragments for this wave's gate/columns: 32 x short8 = 128 VGPRs
  int ecol = wid * 1024 + d0 + (lane & 15);
  int kb = (lane >> 4) * 8;
  short8 u[32];
#pragma unroll
  for (int kk = 0; kk < 32; kk++)
    u[kk] = *(const short8*)(Ub + (size_t)ecol * DD + kk * 32 + kb);

  // zero-init both h buffers (2 x 16 x 1024 bf16) — fresh state every call
  for (int i = tid + bl * 256; i < 2 * 16 * 1024; i += 64 * 256) hbuf[i] = 0;

  // per-thread recurrent state (threads 0..127: b = tid>>4, d = d0 + (tid&15))
  float c_s = 0.0f, n_s = 1.0f;
  int ub = tid >> 4, ud = tid & 15;

  __threadfence();
  grid.sync();

  for (int s = 0; s < SS; s++) {
    const unsigned short* hprev = hbuf + (s & 1) * 16384;
    unsigned short* hnext = hbuf + ((s & 1) ^ 1) * 16384;

    // stage h -> LDS (swizzled): 2048 16B chunks, 8 per thread
    {
      const uint4_t* hg = (const uint4_t*)hprev;
#pragma unroll
      for (int cI = 0; cI < 8; cI++) {
        int chunk = tid + cI * 256;            // 0..2047
        int row = chunk >> 7, off16 = chunk & 127;
        uint4_t val = hg[chunk];
        int byte = (row * 2048 + off16 * 16) ^ ((row & 7) << 4);
        *(uint4_t*)((char*)h_lds + byte) = val;
      }
    }
    __syncthreads();

    // gates = h @ U^T  (M=16 batch-padded, N=16 cols, K=1024)
    f32x4 acc = {0.0f, 0.0f, 0.0f, 0.0f};
    int arow = lane & 15;
#pragma unroll
    for (int kk = 0; kk < 32; kk++) {
      int byte = (arow * 2048 + (kk * 32 + kb) * 2) ^ ((arow & 7) << 4);
      short8 af = *(const short8*)((char*)h_lds + byte);
      acc = __builtin_amdgcn_mfma_f32_16x16x32_bf16(af, u[kk], acc, 0, 0, 0);
    }

    // add xw, publish gates to LDS (valid batches only)
    const unsigned short* xwrow = xw + (size_t)s * (BB * EE);
#pragma unroll
    for (int r2 = 0; r2 < 4; r2++) {
      int b = (lane >> 4) * 4 + r2;
      if (b < BB) {
        float g = acc[r2] + bf2f(xwrow[b * EE + wid * 1024 + d0 + (lane & 15)]);
        g_lds[wid][b][lane & 15] = g;
      }
    }
    __syncthreads();

    // state update + fused output write (128 threads)
    if (tid < BB * 16) {
      float gi = g_lds[0][ub][ud], gf = g_lds[1][ub][ud];
      float go = g_lds[2][ub][ud], gz = g_lds[3][ub][ud];
      float it = expf(gi);
      float ft = 1.0f / (1.0f + expf(-gf));
      float ot = 1.0f / (1.0f + expf(-go));
      float zt = tanhf(gz);
      c_s = ft * c_s + it * zt;
      n_s = ft * n_s + it;
      float h = ot * (c_s / (n_s + 1e-6f));
      hnext[ub * DD + d0 + ud] = f2bf(h);
      size_t oi = (size_t)ub * (SS * DD) + (size_t)s * DD + d0 + ud;
      out[oi] = x[oi] + h;
    }
    __threadfence();
    grid.sync();
  }
}

// ---------------- launch ----------------
extern "C" void kernel_launch(void* const* d_in, const int* in_sizes, int n_in,
                              void* d_out, int out_size, void* d_ws, size_t ws_size,
                              hipStream_t stream) {
  const float* xp = (const float*)d_in[0];
  const float* Wwf = (const float*)d_in[1];
  const float* Wbias = (const float*)d_in[2];
  const float* Uwf = (const float*)d_in[3];
  const float* gamma = (const float*)d_in[4];
  const float* beta = (const float*)d_in[5];
  float* outp = (float*)d_out;

  char* w = (char*)d_ws;
  unsigned short* Wb = (unsigned short*)(w);                    // 8,388,608 B
  unsigned short* Ub = (unsigned short*)(w + 8388608);          // 8,388,608 B
  unsigned short* hout = (unsigned short*)(w + 16777216);       // 33,554,432 B
  unsigned short* xw = (unsigned short*)(w + 50331648);         // 134,217,728 B
  unsigned short* hbuf = (unsigned short*)(w + 184549376);      // 65,536 B

  hipLaunchKernelGGL(cvt2_kernel, dim3(1024), dim3(256), 0, stream, Wwf, Uwf, Wb, Ub);
  hipLaunchKernelGGL(ln_kernel, dim3(BB * SS), dim3(256), 0, stream, xp, gamma, beta, hout);
  hipLaunchKernelGGL(gemm_xw, dim3(1024, 16), dim3(256), 0, stream, hout, Wb, Wbias, xw);

  void* args[5];
  const unsigned short* xw_c = xw;
  const unsigned short* ub_c = Ub;
  args[0] = (void*)&xw_c;
  args[1] = (void*)&ub_c;
  args[2] = (void*)&xp;
  args[3] = (void*)&outp;
  args[4] = (void*)&hbuf;
  hipLaunchCooperativeKernel((void*)scan_kernel, dim3(64), dim3(256), args, 0, stream);
}

// Round 2
// 18470.375 us; speedup vs baseline: 1.9491x; 1.9491x over previous
//
#include <hip/hip_runtime.h>
#include <hip/hip_bf16.h>
#include <hip/hip_cooperative_groups.h>

namespace cg = cooperative_groups;

typedef __attribute__((ext_vector_type(8))) short short8;
typedef __attribute__((ext_vector_type(4))) float f32x4;
typedef __attribute__((ext_vector_type(4))) unsigned int uint4_t;
typedef __attribute__((ext_vector_type(4))) unsigned short ushort4_t;

#define BB 8
#define SS 2048
#define DD 1024
#define EE 4096
#define NB 64  // scan blocks

__device__ __forceinline__ unsigned short f2bf(float f) {
  unsigned int u = __builtin_bit_cast(unsigned int, f);
  u += 0x7fffu + ((u >> 16) & 1u);
  return (unsigned short)(u >> 16);
}
__device__ __forceinline__ float bf2f(unsigned short h) {
  unsigned int u = ((unsigned int)h) << 16;
  return __builtin_bit_cast(float, u);
}

// ---------------- Kernel 1: cast W_w and U_w fp32 -> bf16 ----------------
__global__ void cvt2_kernel(const float* __restrict__ Wf, const float* __restrict__ Uf,
                            unsigned short* __restrict__ Wb, unsigned short* __restrict__ Ub) {
  const int n4 = EE * DD / 4;
  for (int i = blockIdx.x * blockDim.x + threadIdx.x; i < n4; i += gridDim.x * blockDim.x) {
    float4 w = ((const float4*)Wf)[i];
    float4 u = ((const float4*)Uf)[i];
    ushort4_t wo, uo;
    wo[0] = f2bf(w.x); wo[1] = f2bf(w.y); wo[2] = f2bf(w.z); wo[3] = f2bf(w.w);
    uo[0] = f2bf(u.x); uo[1] = f2bf(u.y); uo[2] = f2bf(u.z); uo[3] = f2bf(u.w);
    ((ushort4_t*)Wb)[i] = wo;
    ((ushort4_t*)Ub)[i] = uo;
  }
}

// ---------------- Kernel 2: LayerNorm -> bf16 h_out ----------------
__global__ void ln_kernel(const float* __restrict__ x, const float* __restrict__ gamma,
                          const float* __restrict__ beta, unsigned short* __restrict__ hout) {
  int row = blockIdx.x;
  int t = threadIdx.x;
  int wid = t >> 6, lane = t & 63;
  float4 v = ((const float4*)(x + (size_t)row * DD))[t];
  float s = v.x + v.y + v.z + v.w;
  float s2 = v.x * v.x + v.y * v.y + v.z * v.z + v.w * v.w;
  for (int o = 32; o; o >>= 1) { s += __shfl_down(s, o); s2 += __shfl_down(s2, o); }
  __shared__ float rs[4], rq[4];
  if (lane == 0) { rs[wid] = s; rq[wid] = s2; }
  __syncthreads();
  float sum = rs[0] + rs[1] + rs[2] + rs[3];
  float sum2 = rq[0] + rq[1] + rq[2] + rq[3];
  float mean = sum * (1.0f / DD);
  float var = sum2 * (1.0f / DD) - mean * mean;
  float rstd = rsqrtf(var + 1e-5f);
  float4 g = ((const float4*)gamma)[t];
  float4 bt = ((const float4*)beta)[t];
  ushort4_t o4;
  o4[0] = f2bf((v.x - mean) * rstd * g.x + bt.x);
  o4[1] = f2bf((v.y - mean) * rstd * g.y + bt.y);
  o4[2] = f2bf((v.z - mean) * rstd * g.z + bt.z);
  o4[3] = f2bf((v.w - mean) * rstd * g.w + bt.w);
  ((ushort4_t*)(hout + (size_t)row * DD))[t] = o4;
}

// ---------------- Kernel 3: GEMM xW[s,b,e] = hout[(b,s),:] . W_w[e,:] + W_b[e] ----------------
__launch_bounds__(256)
__global__ void gemm_xw(const unsigned short* __restrict__ A, const unsigned short* __restrict__ Bm,
                        const float* __restrict__ bias, unsigned short* __restrict__ xw) {
  int rowTile = blockIdx.x;
  int colGrp = blockIdx.y;
  int wid = threadIdx.x >> 6;
  int lane = threadIdx.x & 63;
  int colBase = colGrp * 256 + wid * 64;
  int r = rowTile * 16 + (lane & 15);
  int kb = (lane >> 4) * 8;
  f32x4 acc[4] = {};
  for (int k0 = 0; k0 < DD; k0 += 32) {
    short8 af = *(const short8*)(A + (size_t)r * DD + k0 + kb);
#pragma unroll
    for (int c = 0; c < 4; c++) {
      int col = colBase + c * 16 + (lane & 15);
      short8 bf = *(const short8*)(Bm + (size_t)col * DD + k0 + kb);
      acc[c] = __builtin_amdgcn_mfma_f32_16x16x32_bf16(af, bf, acc[c], 0, 0, 0);
    }
  }
#pragma unroll
  for (int c = 0; c < 4; c++) {
    int col = colBase + c * 16 + (lane & 15);
    float bv = bias[col];
#pragma unroll
    for (int r2 = 0; r2 < 4; r2++) {
      int R = rowTile * 16 + (lane >> 4) * 4 + r2;
      int b = R >> 11, sIdx = R & 2047;
      xw[(size_t)sIdx * (BB * EE) + (size_t)b * EE + col] = f2bf(acc[c][r2] + bv);
    }
  }
}

// ---------------- Kernel 4: sLSTM scan — distributed flag sync ----------------
// 64 blocks x 256 thr (4 waves). Block bl owns d in [bl*16, bl*16+16).
// Wave g owns gate g (16 e-cols), U slice pinned in 128 VGPRs.
// h state: 8 x 1024 bf16 (16KB) double-buffered in global; per-block flags, one-sided.
__launch_bounds__(256, 1)
__global__ void scan_kernel(const unsigned short* __restrict__ xw, const unsigned short* __restrict__ Ub,
                            const float* __restrict__ x, float* __restrict__ out,
                            unsigned short* __restrict__ hbuf, int* __restrict__ flags) {
  int bl = blockIdx.x;
  int tid = threadIdx.x;
  int wid = tid >> 6, lane = tid & 63;
  int d0 = bl * 16;

  __shared__ __align__(16) unsigned short h_lds[8 * 1024];  // 16KB, XOR-swizzled
  __shared__ float g_lds[4][8][16];

  // preload U fragments: wave wid, e-cols wid*1024 + d0 + 0..15 -> 32 x short8 (128 VGPRs)
  int ecol = wid * 1024 + d0 + (lane & 15);
  int kb = (lane >> 4) * 8;
  short8 u[32];
#pragma unroll
  for (int kk = 0; kk < 32; kk++)
    u[kk] = *(const short8*)(Ub + (size_t)ecol * DD + kk * 32 + kb);
#pragma unroll
  for (int kk = 0; kk < 32; kk++)
    asm volatile("" : "+v"(u[kk]));  // pin in VGPRs; forbid remat/reload

  float c_s = 0.0f, n_s = 1.0f;
  int ub = tid >> 4, ud = tid & 15;  // update-thread coords (tid < 128)
  bool upd = tid < BB * 16;
  int arow = lane & 7;               // A row (rows 8..15 duplicate 0..7; C rows 8..15 unused)
  int bq = (lane >> 4) * 4;          // C-frag row group (batch base)

  for (int s = 0; s < SS; s++) {
    // ---- prefetch step-s operands (independent of h) before the poll ----
    const unsigned short* xwp = xw + (size_t)s * (BB * EE) + (size_t)wid * 1024 + d0 + (lane & 15);
    unsigned short xv[4] = {0, 0, 0, 0};
    if (bq < BB) {
#pragma unroll
      for (int r2 = 0; r2 < 4; r2++) xv[r2] = xwp[(size_t)(bq + r2) * EE];
    }
    float xin = 0.0f;
    size_t oi = 0;
    if (upd) {
      oi = (size_t)ub * (SS * DD) + (size_t)s * DD + d0 + ud;
      xin = x[oi];
    }

    // ---- one-sided wait: all 64 block flags >= s ----
    if (s != 0) {
      int f = __hip_atomic_load(flags + lane * 32, __ATOMIC_RELAXED, __HIP_MEMORY_SCOPE_AGENT);
      while (__any(f < s)) {
        f = __hip_atomic_load(flags + lane * 32, __ATOMIC_RELAXED, __HIP_MEMORY_SCOPE_AGENT);
      }
    }
    __builtin_amdgcn_fence(__ATOMIC_ACQUIRE, "agent");  // invalidate stale L1/L2

    // ---- stage h (8 x 1024 bf16 = 16KB) -> swizzled LDS ----
    {
      const uint4_t* hg = (const uint4_t*)(hbuf + (size_t)(s & 1) * (BB * DD));
#pragma unroll
      for (int cI = 0; cI < 4; cI++) {
        int chunk = tid + cI * 256;        // 0..1023
        int row = chunk >> 7, off16 = chunk & 127;
        uint4_t val = hg[chunk];
        int byte = (row * 2048 + off16 * 16) ^ (row << 4);
        *(uint4_t*)((char*)h_lds + byte) = val;
      }
    }
    __syncthreads();

    // ---- gates = h @ U^T : 32 MFMAs, 4 independent chains ----
    f32x4 a0 = {}, a1 = {}, a2 = {}, a3 = {};
#pragma unroll
    for (int kk = 0; kk < 32; kk += 4) {
      int base = arow * 2048 + (kk * 32 + kb) * 2;
      short8 f0 = *(const short8*)((char*)h_lds + ((base) ^ (arow << 4)));
      short8 f1 = *(const short8*)((char*)h_lds + ((base + 64) ^ (arow << 4)));
      short8 f2 = *(const short8*)((char*)h_lds + ((base + 128) ^ (arow << 4)));
      short8 f3 = *(const short8*)((char*)h_lds + ((base + 192) ^ (arow << 4)));
      a0 = __builtin_amdgcn_mfma_f32_16x16x32_bf16(f0, u[kk], a0, 0, 0, 0);
      a1 = __builtin_amdgcn_mfma_f32_16x16x32_bf16(f1, u[kk + 1], a1, 0, 0, 0);
      a2 = __builtin_amdgcn_mfma_f32_16x16x32_bf16(f2, u[kk + 2], a2, 0, 0, 0);
      a3 = __builtin_amdgcn_mfma_f32_16x16x32_bf16(f3, u[kk + 3], a3, 0, 0, 0);
    }
    f32x4 acc = (a0 + a1) + (a2 + a3);

    // ---- publish gates (valid batches) ----
    if (bq < BB) {
#pragma unroll
      for (int r2 = 0; r2 < 4; r2++)
        g_lds[wid][bq + r2][lane & 15] = acc[r2] + bf2f(xv[r2]);
    }
    __syncthreads();

    // ---- state update + h publish + fused output ----
    if (upd) {
      float gi = g_lds[0][ub][ud], gf = g_lds[1][ub][ud];
      float go = g_lds[2][ub][ud], gz = g_lds[3][ub][ud];
      float it = expf(gi);
      float ft = 1.0f / (1.0f + expf(-gf));
      float ot = 1.0f / (1.0f + expf(-go));
      float zt = tanhf(gz);
      c_s = ft * c_s + it * zt;
      n_s = ft * n_s + it;
      float h = ot * (c_s / (n_s + 1e-6f));
      __hip_atomic_store(hbuf + (size_t)((s + 1) & 1) * (BB * DD) + ub * DD + d0 + ud,
                         f2bf(h), __ATOMIC_RELAXED, __HIP_MEMORY_SCOPE_AGENT);
      __builtin_nontemporal_store(xin + h, out + oi);
    }
    __threadfence();     // flush/order h stores to agent coherence point
    __syncthreads();     // all waves' stores drained before flag
    if (tid == 0)
      __hip_atomic_store(flags + bl * 32, s + 1, __ATOMIC_RELAXED, __HIP_MEMORY_SCOPE_AGENT);
  }
}

// ---------------- launch ----------------
extern "C" void kernel_launch(void* const* d_in, const int* in_sizes, int n_in,
                              void* d_out, int out_size, void* d_ws, size_t ws_size,
                              hipStream_t stream) {
  const float* xp = (const float*)d_in[0];
  const float* Wwf = (const float*)d_in[1];
  const float* Wbias = (const float*)d_in[2];
  const float* Uwf = (const float*)d_in[3];
  const float* gamma = (const float*)d_in[4];
  const float* beta = (const float*)d_in[5];
  float* outp = (float*)d_out;

  char* w = (char*)d_ws;
  unsigned short* Wb = (unsigned short*)(w);                 // 8 MB
  unsigned short* Ub = (unsigned short*)(w + 8388608);       // 8 MB
  unsigned short* hout = (unsigned short*)(w + 16777216);    // 32 MB
  unsigned short* xw = (unsigned short*)(w + 50331648);      // 128 MB
  unsigned short* hbuf = (unsigned short*)(w + 184549376);   // 32 KB (2 x 8 x 1024 bf16)
  int* flags = (int*)(w + 184549376 + 32768);                // 64 flags, 128B apart

  hipMemsetAsync((void*)hbuf, 0, 32768 + 8192, stream);      // zero h state + flags every call

  hipLaunchKernelGGL(cvt2_kernel, dim3(1024), dim3(256), 0, stream, Wwf, Uwf, Wb, Ub);
  hipLaunchKernelGGL(ln_kernel, dim3(BB * SS), dim3(256), 0, stream, xp, gamma, beta, hout);
  hipLaunchKernelGGL(gemm_xw, dim3(1024, 16), dim3(256), 0, stream, hout, Wb, Wbias, xw);

  void* args[6];
  const unsigned short* xw_c = xw;
  const unsigned short* ub_c = Ub;
  args[0] = (void*)&xw_c;
  args[1] = (void*)&ub_c;
  args[2] = (void*)&xp;
  args[3] = (void*)&outp;
  args[4] = (void*)&hbuf;
  args[5] = (void*)&flags;
  hipLaunchCooperativeKernel((void*)scan_kernel, dim3(NB), dim3(256), args, 0, stream);
}

// Round 4
// 11660.456 us; speedup vs baseline: 3.0874x; 1.5840x over previous
//
#include <hip/hip_runtime.h>
#include <hip/hip_bf16.h>
#include <hip/hip_cooperative_groups.h>

typedef __attribute__((ext_vector_type(8))) short short8;
typedef __attribute__((ext_vector_type(4))) float f32x4;
typedef __attribute__((ext_vector_type(4))) unsigned int uint4_t;
typedef __attribute__((ext_vector_type(4))) unsigned short ushort4_t;

#define BB 8
#define SS 2048
#define DD 1024
#define EE 4096
#define NB 64

__device__ __forceinline__ unsigned short f2bf(float f) {
  unsigned int u = __builtin_bit_cast(unsigned int, f);
  u += 0x7fffu + ((u >> 16) & 1u);
  return (unsigned short)(u >> 16);
}
__device__ __forceinline__ float bf2f(unsigned short h) {
  unsigned int u = ((unsigned int)h) << 16;
  return __builtin_bit_cast(float, u);
}

// ---------------- Kernel 1: cast W_w and U_w fp32 -> bf16 ----------------
__global__ void cvt2_kernel(const float* __restrict__ Wf, const float* __restrict__ Uf,
                            unsigned short* __restrict__ Wb, unsigned short* __restrict__ Ub) {
  const int n4 = EE * DD / 4;
  for (int i = blockIdx.x * blockDim.x + threadIdx.x; i < n4; i += gridDim.x * blockDim.x) {
    float4 w = ((const float4*)Wf)[i];
    float4 u = ((const float4*)Uf)[i];
    ushort4_t wo, uo;
    wo[0] = f2bf(w.x); wo[1] = f2bf(w.y); wo[2] = f2bf(w.z); wo[3] = f2bf(w.w);
    uo[0] = f2bf(u.x); uo[1] = f2bf(u.y); uo[2] = f2bf(u.z); uo[3] = f2bf(u.w);
    ((ushort4_t*)Wb)[i] = wo;
    ((ushort4_t*)Ub)[i] = uo;
  }
}

// ---------------- Kernel 2: LayerNorm -> bf16 h_out ----------------
__global__ void ln_kernel(const float* __restrict__ x, const float* __restrict__ gamma,
                          const float* __restrict__ beta, unsigned short* __restrict__ hout) {
  int row = blockIdx.x;
  int t = threadIdx.x;
  int wid = t >> 6, lane = t & 63;
  float4 v = ((const float4*)(x + (size_t)row * DD))[t];
  float s = v.x + v.y + v.z + v.w;
  float s2 = v.x * v.x + v.y * v.y + v.z * v.z + v.w * v.w;
  for (int o = 32; o; o >>= 1) { s += __shfl_down(s, o); s2 += __shfl_down(s2, o); }
  __shared__ float rs[4], rq[4];
  if (lane == 0) { rs[wid] = s; rq[wid] = s2; }
  __syncthreads();
  float sum = rs[0] + rs[1] + rs[2] + rs[3];
  float sum2 = rq[0] + rq[1] + rq[2] + rq[3];
  float mean = sum * (1.0f / DD);
  float var = sum2 * (1.0f / DD) - mean * mean;
  float rstd = rsqrtf(var + 1e-5f);
  float4 g = ((const float4*)gamma)[t];
  float4 bt = ((const float4*)beta)[t];
  ushort4_t o4;
  o4[0] = f2bf((v.x - mean) * rstd * g.x + bt.x);
  o4[1] = f2bf((v.y - mean) * rstd * g.y + bt.y);
  o4[2] = f2bf((v.z - mean) * rstd * g.z + bt.z);
  o4[3] = f2bf((v.w - mean) * rstd * g.w + bt.w);
  ((ushort4_t*)(hout + (size_t)row * DD))[t] = o4;
}

// ---------------- Kernel 3: GEMM xW[s,b,e] = hout[(b,s),:] . W_w[e,:] + W_b[e] ----------------
__launch_bounds__(256)
__global__ void gemm_xw(const unsigned short* __restrict__ A, const unsigned short* __restrict__ Bm,
                        const float* __restrict__ bias, unsigned short* __restrict__ xw) {
  int rowTile = blockIdx.x;
  int colGrp = blockIdx.y;
  int wid = threadIdx.x >> 6;
  int lane = threadIdx.x & 63;
  int colBase = colGrp * 256 + wid * 64;
  int r = rowTile * 16 + (lane & 15);
  int kb = (lane >> 4) * 8;
  f32x4 acc[4] = {};
  for (int k0 = 0; k0 < DD; k0 += 32) {
    short8 af = *(const short8*)(A + (size_t)r * DD + k0 + kb);
#pragma unroll
    for (int c = 0; c < 4; c++) {
      int col = colBase + c * 16 + (lane & 15);
      short8 bf = *(const short8*)(Bm + (size_t)col * DD + k0 + kb);
      acc[c] = __builtin_amdgcn_mfma_f32_16x16x32_bf16(af, bf, acc[c], 0, 0, 0);
    }
  }
#pragma unroll
  for (int c = 0; c < 4; c++) {
    int col = colBase + c * 16 + (lane & 15);
    float bv = bias[col];
#pragma unroll
    for (int r2 = 0; r2 < 4; r2++) {
      int R = rowTile * 16 + (lane >> 4) * 4 + r2;
      int b = R >> 11, sIdx = R & 2047;
      xw[(size_t)sIdx * (BB * EE) + (size_t)b * EE + col] = f2bf(acc[c][r2] + bv);
    }
  }
}

// ---------------- Kernel 4: sLSTM scan — flag sync, fence-free acquire ----------------
// 64 blocks x 256 thr (4 waves). Block bl owns d in [bl*16, bl*16+16).
// Wave g owns gate g (16 e-cols), U slice pinned in 128 VGPRs.
// h state: 8 x 1024 bf16 double-buffered in global. Acquire side = per-access
// coherent (relaxed agent atomic) loads; NO cache-invalidate fence.
__launch_bounds__(256, 1)
__global__ void scan_kernel(const unsigned short* __restrict__ xw, const unsigned short* __restrict__ Ub,
                            const float* __restrict__ x, float* __restrict__ out,
                            unsigned short* __restrict__ hbuf, int* __restrict__ flags) {
  int bl = blockIdx.x;
  int tid = threadIdx.x;
  int wid = tid >> 6, lane = tid & 63;
  int d0 = bl * 16;

  __shared__ __align__(16) unsigned short h_lds[8 * 1024];  // 16KB, XOR-swizzled
  __shared__ float g_lds[4][8][16];

  // preload U fragments: wave wid, e-cols wid*1024 + d0 + 0..15 -> 32 x short8
  int ecol = wid * 1024 + d0 + (lane & 15);
  int kb = (lane >> 4) * 8;
  short8 u[32];
#pragma unroll
  for (int kk = 0; kk < 32; kk++)
    u[kk] = *(const short8*)(Ub + (size_t)ecol * DD + kk * 32 + kb);
#pragma unroll
  for (int kk = 0; kk < 32; kk++)
    asm volatile("" : "+v"(u[kk]));  // pin; forbid remat/reload

  float c_s = 0.0f, n_s = 1.0f;
  int ub = tid >> 4, ud = tid & 15;  // update-thread coords (tid < 128)
  bool upd = tid < BB * 16;
  int arow = lane & 7;               // A rows 8..15 duplicate 0..7 (C rows 8..15 unused)
  int bq = (lane >> 4) * 4;          // C-frag batch base

  for (int s = 0; s < SS; s++) {
    // ---- prefetch step-s operands (independent of h) before the poll ----
    const unsigned short* xwp = xw + (size_t)s * (BB * EE) + (size_t)wid * 1024 + d0 + (lane & 15);
    unsigned short xv[4] = {0, 0, 0, 0};
    if (bq < BB) {
#pragma unroll
      for (int r2 = 0; r2 < 4; r2++) xv[r2] = xwp[(size_t)(bq + r2) * EE];
    }
    float xin = 0.0f;
    size_t oi = 0;
    if (upd) {
      oi = (size_t)ub * (SS * DD) + (size_t)s * DD + d0 + ud;
      xin = x[oi];
    }

    // ---- one-sided wait: all 64 block flags >= s (all waves poll; coherent loads) ----
    if (s != 0) {
      int f = __hip_atomic_load(flags + lane * 32, __ATOMIC_RELAXED, __HIP_MEMORY_SCOPE_AGENT);
      while (__any(f < s)) {
        f = __hip_atomic_load(flags + lane * 32, __ATOMIC_RELAXED, __HIP_MEMORY_SCOPE_AGENT);
      }
    }
    // NO acquire fence: h is read below via per-access coherent atomic loads.

    // ---- stage h (8 x 1024 bf16 = 16KB) -> swizzled LDS via coherent dword loads ----
    {
      const unsigned int* hg = (const unsigned int*)(hbuf + (size_t)(s & 1) * (BB * DD));
      unsigned int tmp[16];
#pragma unroll
      for (int i = 0; i < 16; i++)
        tmp[i] = __hip_atomic_load(hg + tid + i * 256, __ATOMIC_RELAXED, __HIP_MEMORY_SCOPE_AGENT);
#pragma unroll
      for (int i = 0; i < 16; i++) {
        int dw = tid + i * 256;              // 0..4095
        int row = dw >> 9;                   // 512 dwords per 2KB row
        int byte = (row * 2048 + (dw & 511) * 4) ^ (row << 4);
        *(unsigned int*)((char*)h_lds + byte) = tmp[i];
      }
    }
    __syncthreads();

    // ---- gates = h @ U^T : 32 MFMAs, 4 independent chains ----
    f32x4 a0 = {}, a1 = {}, a2 = {}, a3 = {};
#pragma unroll
    for (int kk = 0; kk < 32; kk += 4) {
      int base = arow * 2048 + (kk * 32 + kb) * 2;
      short8 f0 = *(const short8*)((char*)h_lds + ((base) ^ (arow << 4)));
      short8 f1 = *(const short8*)((char*)h_lds + ((base + 64) ^ (arow << 4)));
      short8 f2 = *(const short8*)((char*)h_lds + ((base + 128) ^ (arow << 4)));
      short8 f3 = *(const short8*)((char*)h_lds + ((base + 192) ^ (arow << 4)));
      a0 = __builtin_amdgcn_mfma_f32_16x16x32_bf16(f0, u[kk], a0, 0, 0, 0);
      a1 = __builtin_amdgcn_mfma_f32_16x16x32_bf16(f1, u[kk + 1], a1, 0, 0, 0);
      a2 = __builtin_amdgcn_mfma_f32_16x16x32_bf16(f2, u[kk + 2], a2, 0, 0, 0);
      a3 = __builtin_amdgcn_mfma_f32_16x16x32_bf16(f3, u[kk + 3], a3, 0, 0, 0);
    }
    f32x4 acc = (a0 + a1) + (a2 + a3);

    // ---- publish gates (valid batches) ----
    if (bq < BB) {
#pragma unroll
      for (int r2 = 0; r2 < 4; r2++)
        g_lds[wid][bq + r2][lane & 15] = acc[r2] + bf2f(xv[r2]);
    }
    __syncthreads();

    // ---- state update + h publish + fused output ----
    if (upd) {
      float gi = g_lds[0][ub][ud], gf = g_lds[1][ub][ud];
      float go = g_lds[2][ub][ud], gz = g_lds[3][ub][ud];
      float it = expf(gi);
      float ft = 1.0f / (1.0f + expf(-gf));
      float ot = 1.0f / (1.0f + expf(-go));
      float zt = tanhf(gz);
      c_s = ft * c_s + it * zt;
      n_s = ft * n_s + it;
      float h = ot * (c_s / (n_s + 1e-6f));
      __hip_atomic_store(hbuf + (size_t)((s + 1) & 1) * (BB * DD) + ub * DD + d0 + ud,
                         f2bf(h), __ATOMIC_RELAXED, __HIP_MEMORY_SCOPE_AGENT);
      __builtin_nontemporal_store(xin + h, out + oi);
      __threadfence();   // release: h stores drained to coherence point (storing waves only)
    }
    __syncthreads();     // join all waves after stores drained
    if (tid == 0)
      __hip_atomic_store(flags + bl * 32, s + 1, __ATOMIC_RELAXED, __HIP_MEMORY_SCOPE_AGENT);
  }
}

// ---------------- launch ----------------
extern "C" void kernel_launch(void* const* d_in, const int* in_sizes, int n_in,
                              void* d_out, int out_size, void* d_ws, size_t ws_size,
                              hipStream_t stream) {
  const float* xp = (const float*)d_in[0];
  const float* Wwf = (const float*)d_in[1];
  const float* Wbias = (const float*)d_in[2];
  const float* Uwf = (const float*)d_in[3];
  const float* gamma = (const float*)d_in[4];
  const float* beta = (const float*)d_in[5];
  float* outp = (float*)d_out;

  char* w = (char*)d_ws;
  unsigned short* Wb = (unsigned short*)(w);                 // 8 MB
  unsigned short* Ub = (unsigned short*)(w + 8388608);       // 8 MB
  unsigned short* hout = (unsigned short*)(w + 16777216);    // 32 MB
  unsigned short* xw = (unsigned short*)(w + 50331648);      // 128 MB
  unsigned short* hbuf = (unsigned short*)(w + 184549376);   // 32 KB (2 x 8 x 1024 bf16)
  int* flags = (int*)(w + 184549376 + 32768);                // 64 flags, 128B apart

  hipMemsetAsync((void*)hbuf, 0, 32768 + 8192, stream);      // zero h state + flags every call

  hipLaunchKernelGGL(cvt2_kernel, dim3(1024), dim3(256), 0, stream, Wwf, Uwf, Wb, Ub);
  hipLaunchKernelGGL(ln_kernel, dim3(BB * SS), dim3(256), 0, stream, xp, gamma, beta, hout);
  hipLaunchKernelGGL(gemm_xw, dim3(1024, 16), dim3(256), 0, stream, hout, Wb, Wbias, xw);

  void* args[6];
  const unsigned short* xw_c = xw;
  const unsigned short* ub_c = Ub;
  args[0] = (void*)&xw_c;
  args[1] = (void*)&ub_c;
  args[2] = (void*)&xp;
  args[3] = (void*)&outp;
  args[4] = (void*)&hbuf;
  args[5] = (void*)&flags;
  hipLaunchCooperativeKernel((void*)scan_kernel, dim3(NB), dim3(256), args, 0, stream);
}

// Round 6
// 9068.862 us; speedup vs baseline: 3.9696x; 1.2858x over previous
//
#include <hip/hip_runtime.h>
#include <hip/hip_bf16.h>
#include <hip/hip_cooperative_groups.h>

typedef __attribute__((ext_vector_type(8))) short short8;
typedef __attribute__((ext_vector_type(4))) float f32x4;
typedef __attribute__((ext_vector_type(4))) unsigned int uint4_t;
typedef __attribute__((ext_vector_type(4))) unsigned short ushort4_t;

#define BB 8
#define SS 2048
#define DD 1024
#define EE 4096
#define NB 64

__device__ __forceinline__ unsigned short f2bf(float f) {
  unsigned int u = __builtin_bit_cast(unsigned int, f);
  u += 0x7fffu + ((u >> 16) & 1u);
  return (unsigned short)(u >> 16);
}
__device__ __forceinline__ float bf2f(unsigned short h) {
  unsigned int u = ((unsigned int)h) << 16;
  return __builtin_bit_cast(float, u);
}

// ---------------- Kernel 1: cast W_w and U_w fp32 -> bf16 ----------------
__global__ void cvt2_kernel(const float* __restrict__ Wf, const float* __restrict__ Uf,
                            unsigned short* __restrict__ Wb, unsigned short* __restrict__ Ub) {
  const int n4 = EE * DD / 4;
  for (int i = blockIdx.x * blockDim.x + threadIdx.x; i < n4; i += gridDim.x * blockDim.x) {
    float4 w = ((const float4*)Wf)[i];
    float4 u = ((const float4*)Uf)[i];
    ushort4_t wo, uo;
    wo[0] = f2bf(w.x); wo[1] = f2bf(w.y); wo[2] = f2bf(w.z); wo[3] = f2bf(w.w);
    uo[0] = f2bf(u.x); uo[1] = f2bf(u.y); uo[2] = f2bf(u.z); uo[3] = f2bf(u.w);
    ((ushort4_t*)Wb)[i] = wo;
    ((ushort4_t*)Ub)[i] = uo;
  }
}

// ---------------- Kernel 2: LayerNorm -> bf16 h_out ----------------
__global__ void ln_kernel(const float* __restrict__ x, const float* __restrict__ gamma,
                          const float* __restrict__ beta, unsigned short* __restrict__ hout) {
  int row = blockIdx.x;
  int t = threadIdx.x;
  int wid = t >> 6, lane = t & 63;
  float4 v = ((const float4*)(x + (size_t)row * DD))[t];
  float s = v.x + v.y + v.z + v.w;
  float s2 = v.x * v.x + v.y * v.y + v.z * v.z + v.w * v.w;
  for (int o = 32; o; o >>= 1) { s += __shfl_down(s, o); s2 += __shfl_down(s2, o); }
  __shared__ float rs[4], rq[4];
  if (lane == 0) { rs[wid] = s; rq[wid] = s2; }
  __syncthreads();
  float sum = rs[0] + rs[1] + rs[2] + rs[3];
  float sum2 = rq[0] + rq[1] + rq[2] + rq[3];
  float mean = sum * (1.0f / DD);
  float var = sum2 * (1.0f / DD) - mean * mean;
  float rstd = rsqrtf(var + 1e-5f);
  float4 g = ((const float4*)gamma)[t];
  float4 bt = ((const float4*)beta)[t];
  ushort4_t o4;
  o4[0] = f2bf((v.x - mean) * rstd * g.x + bt.x);
  o4[1] = f2bf((v.y - mean) * rstd * g.y + bt.y);
  o4[2] = f2bf((v.z - mean) * rstd * g.z + bt.z);
  o4[3] = f2bf((v.w - mean) * rstd * g.w + bt.w);
  ((ushort4_t*)(hout + (size_t)row * DD))[t] = o4;
}

// ---------------- Kernel 3: GEMM xW[s,b,e] = hout[(b,s),:] . W_w[e,:] + W_b[e] ----------------
__launch_bounds__(256)
__global__ void gemm_xw(const unsigned short* __restrict__ A, const unsigned short* __restrict__ Bm,
                        const float* __restrict__ bias, unsigned short* __restrict__ xw) {
  int rowTile = blockIdx.x;
  int colGrp = blockIdx.y;
  int wid = threadIdx.x >> 6;
  int lane = threadIdx.x & 63;
  int colBase = colGrp * 256 + wid * 64;
  int r = rowTile * 16 + (lane & 15);
  int kb = (lane >> 4) * 8;
  f32x4 acc[4] = {};
  for (int k0 = 0; k0 < DD; k0 += 32) {
    short8 af = *(const short8*)(A + (size_t)r * DD + k0 + kb);
#pragma unroll
    for (int c = 0; c < 4; c++) {
      int col = colBase + c * 16 + (lane & 15);
      short8 bf = *(const short8*)(Bm + (size_t)col * DD + k0 + kb);
      acc[c] = __builtin_amdgcn_mfma_f32_16x16x32_bf16(af, bf, acc[c], 0, 0, 0);
    }
  }
#pragma unroll
  for (int c = 0; c < 4; c++) {
    int col = colBase + c * 16 + (lane & 15);
    float bv = bias[col];
#pragma unroll
    for (int r2 = 0; r2 < 4; r2++) {
      int R = rowTile * 16 + (lane >> 4) * 4 + r2;
      int b = R >> 11, sIdx = R & 2047;
      xw[(size_t)sIdx * (BB * EE) + (size_t)b * EE + col] = f2bf(acc[c][r2] + bv);
    }
  }
}

// ---------------- Kernel 4: sLSTM scan — flag sync (R4 protocol, unchanged) ----------------
// 64 blocks x 256 thr (4 waves). Block bl owns d in [bl*16, bl*16+16).
// Wave g owns gate g (16 e-cols), U slice in 128 VGPRs (LDS pad forces 1 blk/CU
// -> 512-VGPR budget -> no spill). h: 8x1024 bf16 double-buffered in global.
__launch_bounds__(256, 1)
__global__ void scan_kernel(const unsigned short* __restrict__ xw, const unsigned short* __restrict__ Ub,
                            const float* __restrict__ x, float* __restrict__ out,
                            unsigned short* __restrict__ hbuf, int* __restrict__ flags) {
  int bl = blockIdx.x;
  int tid = threadIdx.x;
  int wid = tid >> 6, lane = tid & 63;
  int d0 = bl * 16;

  __shared__ __align__(16) unsigned short h_lds[8 * 1024];  // 16KB, XOR-swizzled
  __shared__ float g_lds[4][8][16];
  __shared__ char pad_lds[80 * 1024];   // occupancy limiter: 1 block/CU -> 512-VGPR budget
  ((volatile char*)pad_lds)[tid] = 0;   // keep allocation alive

  // preload U fragments: wave wid, e-cols wid*1024 + d0 + 0..15 -> 32 x short8
  int ecol = wid * 1024 + d0 + (lane & 15);
  int kb = (lane >> 4) * 8;
  short8 u[32];
#pragma unroll
  for (int kk = 0; kk < 32; kk++)
    u[kk] = *(const short8*)(Ub + (size_t)ecol * DD + kk * 32 + kb);
#pragma unroll
  for (int kk = 0; kk < 32; kk++)
    asm volatile("" : "+v"(u[kk]));  // pin; forbid remat/reload

  float c_s = 0.0f, n_s = 1.0f;
  int ub = tid >> 4, ud = tid & 15;  // update-thread coords (tid < 128)
  bool upd = tid < BB * 16;
  int arow = lane & 7;               // A rows 8..15 duplicate 0..7 (C rows 8..15 unused)
  int bq = (lane >> 4) * 4;          // C-frag batch base

  for (int s = 0; s < SS; s++) {
    // ---- prefetch step-s operands (independent of h) before the poll ----
    const unsigned short* xwp = xw + (size_t)s * (BB * EE) + (size_t)wid * 1024 + d0 + (lane & 15);
    unsigned short xv[4] = {0, 0, 0, 0};
    if (bq < BB) {
#pragma unroll
      for (int r2 = 0; r2 < 4; r2++) xv[r2] = xwp[(size_t)(bq + r2) * EE];
    }
    float xin = 0.0f;
    size_t oi = 0;
    if (upd) {
      oi = (size_t)ub * (SS * DD) + (size_t)s * DD + d0 + ud;
      xin = x[oi];
    }

    // ---- one-sided wait: all 64 block flags >= s (coherent relaxed loads) ----
    if (s != 0) {
      int f = __hip_atomic_load(flags + lane * 32, __ATOMIC_RELAXED, __HIP_MEMORY_SCOPE_AGENT);
      while (__any(f < s)) {
        f = __hip_atomic_load(flags + lane * 32, __ATOMIC_RELAXED, __HIP_MEMORY_SCOPE_AGENT);
      }
    }

    // ---- stage h (8 x 1024 bf16 = 16KB) -> swizzled LDS via coherent dword loads ----
    {
      const unsigned int* hg = (const unsigned int*)(hbuf + (size_t)(s & 1) * (BB * DD));
      unsigned int tmp[16];
#pragma unroll
      for (int i = 0; i < 16; i++)
        tmp[i] = __hip_atomic_load(hg + tid + i * 256, __ATOMIC_RELAXED, __HIP_MEMORY_SCOPE_AGENT);
#pragma unroll
      for (int i = 0; i < 16; i++) {
        int dw = tid + i * 256;              // 0..4095
        int row = dw >> 9;                   // 512 dwords per 2KB row
        int byte = (row * 2048 + (dw & 511) * 4) ^ (row << 4);
        *(unsigned int*)((char*)h_lds + byte) = tmp[i];
      }
    }
    __syncthreads();

    // ---- gates = h @ U^T : 32 MFMAs, 4 independent chains ----
    f32x4 a0 = {}, a1 = {}, a2 = {}, a3 = {};
#pragma unroll
    for (int kk = 0; kk < 32; kk += 4) {
      int base = arow * 2048 + (kk * 32 + kb) * 2;
      short8 f0 = *(const short8*)((char*)h_lds + ((base) ^ (arow << 4)));
      short8 f1 = *(const short8*)((char*)h_lds + ((base + 64) ^ (arow << 4)));
      short8 f2 = *(const short8*)((char*)h_lds + ((base + 128) ^ (arow << 4)));
      short8 f3 = *(const short8*)((char*)h_lds + ((base + 192) ^ (arow << 4)));
      a0 = __builtin_amdgcn_mfma_f32_16x16x32_bf16(f0, u[kk], a0, 0, 0, 0);
      a1 = __builtin_amdgcn_mfma_f32_16x16x32_bf16(f1, u[kk + 1], a1, 0, 0, 0);
      a2 = __builtin_amdgcn_mfma_f32_16x16x32_bf16(f2, u[kk + 2], a2, 0, 0, 0);
      a3 = __builtin_amdgcn_mfma_f32_16x16x32_bf16(f3, u[kk + 3], a3, 0, 0, 0);
    }
    f32x4 acc = (a0 + a1) + (a2 + a3);

    // ---- publish gates (valid batches) ----
    if (bq < BB) {
#pragma unroll
      for (int r2 = 0; r2 < 4; r2++)
        g_lds[wid][bq + r2][lane & 15] = acc[r2] + bf2f(xv[r2]);
    }
    __syncthreads();

    // ---- state update + coherent h publish (out-store deferred past flag) ----
    float h_val = 0.0f;
    if (upd) {
      float gi = g_lds[0][ub][ud], gf = g_lds[1][ub][ud];
      float go = g_lds[2][ub][ud], gz = g_lds[3][ub][ud];
      float it = __expf(gi);
      float ft = 1.0f / (1.0f + __expf(-gf));
      float ot = 1.0f / (1.0f + __expf(-go));
      float az = fabsf(gz);
      float e2 = __expf(2.0f * az);
      float zt = __builtin_copysignf(1.0f - 2.0f / (e2 + 1.0f), gz);
      c_s = ft * c_s + it * zt;
      n_s = ft * n_s + it;
      h_val = ot * (c_s / (n_s + 1e-6f));
      __hip_atomic_store(hbuf + (size_t)((s + 1) & 1) * (BB * DD) + ub * DD + d0 + ud,
                         f2bf(h_val), __ATOMIC_RELAXED, __HIP_MEMORY_SCOPE_AGENT);
      __threadfence();   // release: h stores drained (out not yet issued -> cheap)
    }
    __syncthreads();     // all waves joined after stores drained
    if (tid == 0)
      __hip_atomic_store(flags + bl * 32, s + 1, __ATOMIC_RELAXED, __HIP_MEMORY_SCOPE_AGENT);
    // ---- fused output write: off the cross-block critical path ----
    if (upd)
      __builtin_nontemporal_store(xin + h_val, out + oi);
  }
}

// ---------------- launch ----------------
extern "C" void kernel_launch(void* const* d_in, const int* in_sizes, int n_in,
                              void* d_out, int out_size, void* d_ws, size_t ws_size,
                              hipStream_t stream) {
  const float* xp = (const float*)d_in[0];
  const float* Wwf = (const float*)d_in[1];
  const float* Wbias = (const float*)d_in[2];
  const float* Uwf = (const float*)d_in[3];
  const float* gamma = (const float*)d_in[4];
  const float* beta = (const float*)d_in[5];
  float* outp = (float*)d_out;

  char* w = (char*)d_ws;
  unsigned short* Wb = (unsigned short*)(w);                 // 8 MB
  unsigned short* Ub = (unsigned short*)(w + 8388608);       // 8 MB
  unsigned short* hout = (unsigned short*)(w + 16777216);    // 32 MB
  unsigned short* xw = (unsigned short*)(w + 50331648);      // 128 MB
  unsigned short* hbuf = (unsigned short*)(w + 184549376);   // 32 KB (2 x 8 x 1024 bf16)
  int* flags = (int*)(w + 184549376 + 32768);                // 64 flags, 128B apart

  hipMemsetAsync((void*)hbuf, 0, 32768 + 8192, stream);      // zero h state + flags every call

  hipLaunchKernelGGL(cvt2_kernel, dim3(1024), dim3(256), 0, stream, Wwf, Uwf, Wb, Ub);
  hipLaunchKernelGGL(ln_kernel, dim3(BB * SS), dim3(256), 0, stream, xp, gamma, beta, hout);
  hipLaunchKernelGGL(gemm_xw, dim3(1024, 16), dim3(256), 0, stream, hout, Wb, Wbias, xw);

  void* args[6];
  const unsigned short* xw_c = xw;
  const unsigned short* ub_c = Ub;
  args[0] = (void*)&xw_c;
  args[1] = (void*)&ub_c;
  args[2] = (void*)&xp;
  args[3] = (void*)&outp;
  args[4] = (void*)&hbuf;
  args[5] = (void*)&flags;
  hipLaunchCooperativeKernel((void*)scan_kernel, dim3(NB), dim3(256), args, 0, stream);
}

// Round 7
// 5865.635 us; speedup vs baseline: 6.1375x; 1.5461x over previous
//
#include <hip/hip_runtime.h>
#include <hip/hip_bf16.h>
#include <hip/hip_cooperative_groups.h>

typedef __attribute__((ext_vector_type(8))) short short8;
typedef __attribute__((ext_vector_type(4))) float f32x4;
typedef __attribute__((ext_vector_type(4))) unsigned int uint4_t;
typedef __attribute__((ext_vector_type(4))) unsigned short ushort4_t;

#define BB 8
#define SS 2048
#define DD 1024
#define EE 4096
#define NB 64

__device__ __forceinline__ unsigned short f2bf(float f) {
  unsigned int u = __builtin_bit_cast(unsigned int, f);
  u += 0x7fffu + ((u >> 16) & 1u);
  return (unsigned short)(u >> 16);
}
__device__ __forceinline__ float bf2f(unsigned short h) {
  unsigned int u = ((unsigned int)h) << 16;
  return __builtin_bit_cast(float, u);
}

// ---------------- Kernel 1: cast W_w and U_w fp32 -> bf16 ----------------
__global__ void cvt2_kernel(const float* __restrict__ Wf, const float* __restrict__ Uf,
                            unsigned short* __restrict__ Wb, unsigned short* __restrict__ Ub) {
  const int n4 = EE * DD / 4;
  for (int i = blockIdx.x * blockDim.x + threadIdx.x; i < n4; i += gridDim.x * blockDim.x) {
    float4 w = ((const float4*)Wf)[i];
    float4 u = ((const float4*)Uf)[i];
    ushort4_t wo, uo;
    wo[0] = f2bf(w.x); wo[1] = f2bf(w.y); wo[2] = f2bf(w.z); wo[3] = f2bf(w.w);
    uo[0] = f2bf(u.x); uo[1] = f2bf(u.y); uo[2] = f2bf(u.z); uo[3] = f2bf(u.w);
    ((ushort4_t*)Wb)[i] = wo;
    ((ushort4_t*)Ub)[i] = uo;
  }
}

// ---------------- Kernel 2: LayerNorm -> bf16 h_out ----------------
__global__ void ln_kernel(const float* __restrict__ x, const float* __restrict__ gamma,
                          const float* __restrict__ beta, unsigned short* __restrict__ hout) {
  int row = blockIdx.x;
  int t = threadIdx.x;
  int wid = t >> 6, lane = t & 63;
  float4 v = ((const float4*)(x + (size_t)row * DD))[t];
  float s = v.x + v.y + v.z + v.w;
  float s2 = v.x * v.x + v.y * v.y + v.z * v.z + v.w * v.w;
  for (int o = 32; o; o >>= 1) { s += __shfl_down(s, o); s2 += __shfl_down(s2, o); }
  __shared__ float rs[4], rq[4];
  if (lane == 0) { rs[wid] = s; rq[wid] = s2; }
  __syncthreads();
  float sum = rs[0] + rs[1] + rs[2] + rs[3];
  float sum2 = rq[0] + rq[1] + rq[2] + rq[3];
  float mean = sum * (1.0f / DD);
  float var = sum2 * (1.0f / DD) - mean * mean;
  float rstd = rsqrtf(var + 1e-5f);
  float4 g = ((const float4*)gamma)[t];
  float4 bt = ((const float4*)beta)[t];
  ushort4_t o4;
  o4[0] = f2bf((v.x - mean) * rstd * g.x + bt.x);
  o4[1] = f2bf((v.y - mean) * rstd * g.y + bt.y);
  o4[2] = f2bf((v.z - mean) * rstd * g.z + bt.z);
  o4[3] = f2bf((v.w - mean) * rstd * g.w + bt.w);
  ((ushort4_t*)(hout + (size_t)row * DD))[t] = o4;
}

// ---------------- Kernel 3: GEMM xW = hout . W_w^T + b, 32 rows/block (B-frag reuse) ----------------
__launch_bounds__(256)
__global__ void gemm_xw(const unsigned short* __restrict__ A, const unsigned short* __restrict__ Bm,
                        const float* __restrict__ bias, unsigned short* __restrict__ xw) {
  int rowTile = blockIdx.x;   // 0..511, 32 rows each
  int colGrp = blockIdx.y;    // 0..15
  int wid = threadIdx.x >> 6;
  int lane = threadIdx.x & 63;
  int colBase = colGrp * 256 + wid * 64;
  int r0 = rowTile * 32 + (lane & 15);
  int kb = (lane >> 4) * 8;
  f32x4 acc[2][4] = {};
  for (int k0 = 0; k0 < DD; k0 += 32) {
    short8 a0 = *(const short8*)(A + (size_t)r0 * DD + k0 + kb);
    short8 a1 = *(const short8*)(A + (size_t)(r0 + 16) * DD + k0 + kb);
#pragma unroll
    for (int c = 0; c < 4; c++) {
      int col = colBase + c * 16 + (lane & 15);
      short8 bf = *(const short8*)(Bm + (size_t)col * DD + k0 + kb);
      acc[0][c] = __builtin_amdgcn_mfma_f32_16x16x32_bf16(a0, bf, acc[0][c], 0, 0, 0);
      acc[1][c] = __builtin_amdgcn_mfma_f32_16x16x32_bf16(a1, bf, acc[1][c], 0, 0, 0);
    }
  }
#pragma unroll
  for (int rr = 0; rr < 2; rr++) {
#pragma unroll
    for (int c = 0; c < 4; c++) {
      int col = colBase + c * 16 + (lane & 15);
      float bv = bias[col];
#pragma unroll
      for (int r2 = 0; r2 < 4; r2++) {
        int R = rowTile * 32 + rr * 16 + (lane >> 4) * 4 + r2;
        int b = R >> 11, sIdx = R & 2047;
        xw[(size_t)sIdx * (BB * EE) + (size_t)b * EE + col] = f2bf(acc[rr][c][r2] + bv);
      }
    }
  }
}

// ---------------- Kernel 4: sLSTM scan — flag sync; release = s_waitcnt only ----------------
// 64 blocks x 256 thr (4 waves). Block bl owns d in [bl*16, bl*16+16).
// Wave g owns gate g (16 e-cols), U slice register/AGPR-resident.
// All cross-block data moves via per-access coherent (sc-flagged) relaxed agent
// atomics -> no cache-maintenance fences needed; release ordering = vmcnt(0).
__launch_bounds__(256, 1)
__global__ void scan_kernel(const unsigned short* __restrict__ xw, const unsigned short* __restrict__ Ub,
                            const float* __restrict__ x, float* __restrict__ out,
                            unsigned short* __restrict__ hbuf, int* __restrict__ flags) {
  int bl = blockIdx.x;
  int tid = threadIdx.x;
  int wid = tid >> 6, lane = tid & 63;
  int d0 = bl * 16;

  __shared__ __align__(16) unsigned short h_lds[8 * 1024];  // 16KB, XOR-swizzled
  __shared__ float g_lds[4][8][16];
  __shared__ char pad_lds[80 * 1024];   // occupancy limiter: 1 block/CU -> big reg budget
  ((volatile char*)pad_lds)[tid] = 0;   // keep allocation alive

  // preload U fragments: wave wid, e-cols wid*1024 + d0 + 0..15 -> 32 x short8
  int ecol = wid * 1024 + d0 + (lane & 15);
  int kb = (lane >> 4) * 8;
  short8 u[32];
#pragma unroll
  for (int kk = 0; kk < 32; kk++)
    u[kk] = *(const short8*)(Ub + (size_t)ecol * DD + kk * 32 + kb);
#pragma unroll
  for (int kk = 0; kk < 32; kk++)
    asm volatile("" : "+v"(u[kk]));  // pin; forbid remat/reload

  float c_s = 0.0f, n_s = 1.0f;
  int ub = tid >> 4, ud = tid & 15;  // update-thread coords (tid < 128)
  bool upd = tid < BB * 16;
  int arow = lane & 7;               // A rows 8..15 duplicate 0..7 (C rows 8..15 unused)
  int bq = (lane >> 4) * 4;          // C-frag batch base

  for (int s = 0; s < SS; s++) {
    // ---- prefetch step-s operands (independent of h) before the poll ----
    const unsigned short* xwp = xw + (size_t)s * (BB * EE) + (size_t)wid * 1024 + d0 + (lane & 15);
    unsigned short xv[4] = {0, 0, 0, 0};
    if (bq < BB) {
#pragma unroll
      for (int r2 = 0; r2 < 4; r2++) xv[r2] = xwp[(size_t)(bq + r2) * EE];
    }
    float xin = 0.0f;
    size_t oi = 0;
    if (upd) {
      oi = (size_t)ub * (SS * DD) + (size_t)s * DD + d0 + ud;
      xin = x[oi];
    }

    // ---- one-sided wait: all 64 block flags >= s (coherent relaxed loads) ----
    if (s != 0) {
      int f = __hip_atomic_load(flags + lane * 32, __ATOMIC_RELAXED, __HIP_MEMORY_SCOPE_AGENT);
      while (__any(f < s)) {
        f = __hip_atomic_load(flags + lane * 32, __ATOMIC_RELAXED, __HIP_MEMORY_SCOPE_AGENT);
      }
    }

    // ---- stage h (8 x 1024 bf16 = 16KB) -> swizzled LDS via coherent dword loads ----
    {
      const unsigned int* hg = (const unsigned int*)(hbuf + (size_t)(s & 1) * (BB * DD));
      unsigned int tmp[16];
#pragma unroll
      for (int i = 0; i < 16; i++)
        tmp[i] = __hip_atomic_load(hg + tid + i * 256, __ATOMIC_RELAXED, __HIP_MEMORY_SCOPE_AGENT);
#pragma unroll
      for (int i = 0; i < 16; i++) {
        int dw = tid + i * 256;              // 0..4095
        int row = dw >> 9;                   // 512 dwords per 2KB row
        int byte = (row * 2048 + (dw & 511) * 4) ^ (row << 4);
        *(unsigned int*)((char*)h_lds + byte) = tmp[i];
      }
    }
    __syncthreads();

    // ---- gates = h @ U^T : 32 MFMAs, 4 independent chains ----
    f32x4 a0 = {}, a1 = {}, a2 = {}, a3 = {};
#pragma unroll
    for (int kk = 0; kk < 32; kk += 4) {
      int base = arow * 2048 + (kk * 32 + kb) * 2;
      short8 f0 = *(const short8*)((char*)h_lds + ((base) ^ (arow << 4)));
      short8 f1 = *(const short8*)((char*)h_lds + ((base + 64) ^ (arow << 4)));
      short8 f2 = *(const short8*)((char*)h_lds + ((base + 128) ^ (arow << 4)));
      short8 f3 = *(const short8*)((char*)h_lds + ((base + 192) ^ (arow << 4)));
      a0 = __builtin_amdgcn_mfma_f32_16x16x32_bf16(f0, u[kk], a0, 0, 0, 0);
      a1 = __builtin_amdgcn_mfma_f32_16x16x32_bf16(f1, u[kk + 1], a1, 0, 0, 0);
      a2 = __builtin_amdgcn_mfma_f32_16x16x32_bf16(f2, u[kk + 2], a2, 0, 0, 0);
      a3 = __builtin_amdgcn_mfma_f32_16x16x32_bf16(f3, u[kk + 3], a3, 0, 0, 0);
    }
    f32x4 acc = (a0 + a1) + (a2 + a3);

    // ---- publish gates (valid batches) ----
    if (bq < BB) {
#pragma unroll
      for (int r2 = 0; r2 < 4; r2++)
        g_lds[wid][bq + r2][lane & 15] = acc[r2] + bf2f(xv[r2]);
    }
    __syncthreads();

    // ---- state update + coherent h publish; release = vmcnt(0) only ----
    float h_val = 0.0f;
    if (upd) {
      float gi = g_lds[0][ub][ud], gf = g_lds[1][ub][ud];
      float go = g_lds[2][ub][ud], gz = g_lds[3][ub][ud];
      float it = __expf(gi);
      float ft = 1.0f / (1.0f + __expf(-gf));
      float ot = 1.0f / (1.0f + __expf(-go));
      float az = fabsf(gz);
      float e2 = __expf(2.0f * az);
      float zt = __builtin_copysignf(1.0f - 2.0f / (e2 + 1.0f), gz);
      c_s = ft * c_s + it * zt;
      n_s = ft * n_s + it;
      h_val = ot * (c_s / (n_s + 1e-6f));
      __hip_atomic_store(hbuf + (size_t)((s + 1) & 1) * (BB * DD) + ub * DD + d0 + ud,
                         f2bf(h_val), __ATOMIC_RELAXED, __HIP_MEMORY_SCOPE_AGENT);
      // release: h-stores are per-access coherent (write-through to coherence
      // point); only completion-ordering vs the flag store is needed.
      asm volatile("s_waitcnt vmcnt(0)" ::: "memory");
    }
    __syncthreads();     // all waves joined after stores drained
    if (tid == 0)
      __hip_atomic_store(flags + bl * 32, s + 1, __ATOMIC_RELAXED, __HIP_MEMORY_SCOPE_AGENT);
    // ---- fused output write: off the cross-block critical path ----
    if (upd)
      __builtin_nontemporal_store(xin + h_val, out + oi);
  }
}

// ---------------- launch ----------------
extern "C" void kernel_launch(void* const* d_in, const int* in_sizes, int n_in,
                              void* d_out, int out_size, void* d_ws, size_t ws_size,
                              hipStream_t stream) {
  const float* xp = (const float*)d_in[0];
  const float* Wwf = (const float*)d_in[1];
  const float* Wbias = (const float*)d_in[2];
  const float* Uwf = (const float*)d_in[3];
  const float* gamma = (const float*)d_in[4];
  const float* beta = (const float*)d_in[5];
  float* outp = (float*)d_out;

  char* w = (char*)d_ws;
  unsigned short* Wb = (unsigned short*)(w);                 // 8 MB
  unsigned short* Ub = (unsigned short*)(w + 8388608);       // 8 MB
  unsigned short* hout = (unsigned short*)(w + 16777216);    // 32 MB
  unsigned short* xw = (unsigned short*)(w + 50331648);      // 128 MB
  unsigned short* hbuf = (unsigned short*)(w + 184549376);   // 32 KB (2 x 8 x 1024 bf16)
  int* flags = (int*)(w + 184549376 + 32768);                // 64 flags, 128B apart

  hipMemsetAsync((void*)hbuf, 0, 32768 + 8192, stream);      // zero h state + flags every call

  hipLaunchKernelGGL(cvt2_kernel, dim3(1024), dim3(256), 0, stream, Wwf, Uwf, Wb, Ub);
  hipLaunchKernelGGL(ln_kernel, dim3(BB * SS), dim3(256), 0, stream, xp, gamma, beta, hout);
  hipLaunchKernelGGL(gemm_xw, dim3(512, 16), dim3(256), 0, stream, hout, Wb, Wbias, xw);

  void* args[6];
  const unsigned short* xw_c = xw;
  const unsigned short* ub_c = Ub;
  args[0] = (void*)&xw_c;
  args[1] = (void*)&ub_c;
  args[2] = (void*)&xp;
  args[3] = (void*)&outp;
  args[4] = (void*)&hbuf;
  args[5] = (void*)&flags;
  hipLaunchCooperativeKernel((void*)scan_kernel, dim3(NB), dim3(256), args, 0, stream);
}